// Round 15
// baseline (138.618 us; speedup 1.0000x reference)
//
#include <hip/hip_runtime.h>

// ---------------------------------------------------------------------------
// LargeWindowAttention on MI355X (gfx950)
// pq -> ln -> mix -> merged QKV GEMM (3-buffer pipelined, counted vmcnt,
// raw barriers) -> window attention (r10 structure) -> out GEMM (pipelined)
// -> relayout.
// ---------------------------------------------------------------------------

typedef __bf16 bf16;
typedef __bf16 bf16x2 __attribute__((ext_vector_type(2)));
typedef __bf16 bf16x4 __attribute__((ext_vector_type(4)));
typedef __bf16 bf16x8 __attribute__((ext_vector_type(8)));
typedef float f32x4 __attribute__((ext_vector_type(4)));

#define MFMA(a, b, c) __builtin_amdgcn_mfma_f32_16x16x32_bf16(a, b, c, 0, 0, 0)

__device__ __forceinline__ void gll16(const void* g, void* l) {
  __builtin_amdgcn_global_load_lds((const __attribute__((address_space(1))) void*)g,
                                   (__attribute__((address_space(3))) void*)l, 16, 0, 0);
}

// ---------------------------------------------------------------------------
__global__ void k_wconv(const float* __restrict__ in_w, const float* __restrict__ out_w,
                        bf16* __restrict__ wib, bf16* __restrict__ wob) {
  int i = blockIdx.x * blockDim.x + threadIdx.x;
  const int n1 = (1536 * 512) / 4;
  float4 v;
  bf16* dst;
  if (i < n1) { v = ((const float4*)in_w)[i];      dst = wib + (size_t)i * 4; }
  else        { v = ((const float4*)out_w)[i - n1]; dst = wob + (size_t)(i - n1) * 4; }
  dst[0] = (bf16)v.x; dst[1] = (bf16)v.y; dst[2] = (bf16)v.z; dst[3] = (bf16)v.w;
}

// ---------------------------------------------------------------------------
__global__ __launch_bounds__(256) void k_pq(const float* __restrict__ x,
                                            float* __restrict__ xp2t,
                                            bf16* __restrict__ qb) {
  __shared__ float xs[2][64][133];
  const int y2 = blockIdx.x, c0 = blockIdx.y * 64, t = threadIdx.x;
  #pragma unroll
  for (int it = 0; it < 16; ++it) {
    int flat = it * 256 + t;
    int ci = flat >> 6, rest = flat & 63;
    int yb = rest >> 5, xq = rest & 31;
    float4 v = *(const float4*)(x + (size_t)(c0 + ci) * 16384 +
                                (size_t)(2 * y2 + yb) * 128 + xq * 4);
    float* d = &xs[yb][ci][xq * 4];
    d[0] = v.x; d[1] = v.y; d[2] = v.z; d[3] = v.w;
  }
  __syncthreads();
  #pragma unroll
  for (int it = 0; it < 16; ++it) {
    int flat = it * 256 + t;
    int x2 = flat >> 6, ci = flat & 63;
    float s = xs[0][ci][2 * x2] + xs[0][ci][2 * x2 + 1] +
              xs[1][ci][2 * x2] + xs[1][ci][2 * x2 + 1];
    xp2t[(size_t)(y2 * 64 + x2) * 512 + c0 + ci] = 0.25f * s;
  }
  #pragma unroll
  for (int yb = 0; yb < 2; ++yb) {
    const int Y = 2 * y2 + yb;
    const int hy = Y >> 3, py = Y & 7;
    #pragma unroll
    for (int it = 0; it < 32; ++it) {
      int flat = it * 256 + t;
      int X = flat >> 6, ci = flat & 63;
      int l = py * 8 + (X & 7), s = hy * 16 + (X >> 3);
      qb[((size_t)l * 256 + s) * 512 + c0 + ci] = (bf16)xs[yb][ci][X];
    }
  }
}

// ---------------------------------------------------------------------------
__global__ __launch_bounds__(512) void k_ln(const float* __restrict__ xp2t,
                                            const float* __restrict__ lnw,
                                            const float* __restrict__ lnb,
                                            bf16* __restrict__ T) {
  __shared__ bf16 Tt[512][24];
  const int s = blockIdx.x, qt = blockIdx.y;
  const int wy = s >> 4, wx = s & 15;
  const int t = threadIdx.x, wv = t >> 6, ln = t & 63;

  float wl[8], bl[8];
  #pragma unroll
  for (int k = 0; k < 8; ++k) { wl[k] = lnw[k * 64 + ln]; bl[k] = lnb[k * 64 + ln]; }

  float v[2][8], mu_[2], rs_[2];
  #pragma unroll
  for (int p = 0; p < 2; ++p) {
    const int l = qt * 16 + wv * 2 + p;
    const int py = l >> 3, px = l & 7;
    const int y2 = wy * 4 - 2 + py, x2 = wx * 4 - 2 + px;
    const bool inb = (y2 >= 0) && (y2 < 64) && (x2 >= 0) && (x2 < 64);
    const float* src = xp2t + (size_t)(y2 * 64 + x2) * 512;
    float sum = 0.f, ssq = 0.f;
    #pragma unroll
    for (int k = 0; k < 8; ++k) {
      float xv = 0.f;
      if (inb) xv = src[k * 64 + ln];
      v[p][k] = xv; sum += xv; ssq += xv * xv;
    }
    #pragma unroll
    for (int off = 1; off < 64; off <<= 1) {
      sum += __shfl_xor(sum, off);
      ssq += __shfl_xor(ssq, off);
    }
    float mu = sum * (1.f / 512.f);
    mu_[p] = mu;
    rs_[p] = rsqrtf(ssq * (1.f / 512.f) - mu * mu + 1e-6f);
  }
  #pragma unroll
  for (int k = 0; k < 8; ++k) {
    const int c = k * 64 + ln;
    bf16x2 u;
    u.x = (bf16)((v[0][k] - mu_[0]) * rs_[0] * wl[k] + bl[k]);
    u.y = (bf16)((v[1][k] - mu_[1]) * rs_[1] * wl[k] + bl[k]);
    *(bf16x2*)(&Tt[c][wv * 2]) = u;
  }
  __syncthreads();
  #pragma unroll
  for (int it = 0; it < 2; ++it) {
    int flat = it * 512 + t;
    int c = flat >> 1, ch = flat & 1;
    bf16x8 u = *(const bf16x8*)(&Tt[c][ch * 8]);
    *(bf16x8*)(T + ((size_t)s * 512 + c) * 64 + qt * 16 + ch * 8) = u;
  }
}

// ---------------------------------------------------------------------------
__global__ __launch_bounds__(256) void k_mix(const bf16* __restrict__ T,
                                             const float* __restrict__ mix_w,
                                             const float* __restrict__ mix_b,
                                             bf16* __restrict__ ctx) {
  const int t = threadIdx.x, wv = t >> 6, ln = t & 63;
  const int s = blockIdx.x, hg = blockIdx.y;
  const int h = hg * 4 + wv;
  const int q = ln >> 4, r = ln & 15;

  bf16x8 a[4][2];
  #pragma unroll
  for (int m = 0; m < 4; ++m) {
    #pragma unroll
    for (int ks = 0; ks < 2; ++ks) {
      const int rm = m * 16 + r;
      const float* wsrc = mix_w + ((size_t)h * 64 + rm) * 64 + ks * 32 + q * 8;
      bf16x8 pk;
      #pragma unroll
      for (int e = 0; e < 8; ++e) {
        int l = ks * 32 + q * 8 + e;
        float w = wsrc[e] + (rm == l ? 1.f : 0.f);
        pk[e] = (bf16)w;
      }
      a[m][ks] = pk;
    }
  }
  const bf16* Tb = T + ((size_t)s * 512 + h * 64) * 64;
  bf16x8 b[4][2];
  #pragma unroll
  for (int n = 0; n < 4; ++n) {
    #pragma unroll
    for (int ks = 0; ks < 2; ++ks)
      b[n][ks] = *(const bf16x8*)(Tb + (size_t)(n * 16 + r) * 64 + ks * 32 + q * 8);
  }
  f32x4 acc[4][4] = {};
  #pragma unroll
  for (int ks = 0; ks < 2; ++ks) {
    #pragma unroll
    for (int m = 0; m < 4; ++m) {
      #pragma unroll
      for (int n = 0; n < 4; ++n) acc[m][n] = MFMA(a[m][ks], b[n][ks], acc[m][n]);
    }
  }
  #pragma unroll
  for (int m = 0; m < 4; ++m) {
    #pragma unroll
    for (int j = 0; j < 4; ++j) {
      const int rm = m * 16 + q * 4 + j;
      const float bias = mix_b[h * 64 + rm];
      #pragma unroll
      for (int n = 0; n < 4; ++n)
        ctx[((size_t)rm * 256 + s) * 512 + h * 64 + n * 16 + r] =
            (bf16)(acc[m][n][j] + bias);
    }
  }
}

// ---------------------------------------------------------------------------
// Pipelined GEMM core: 128x128 tile, BK=32, 3-buffer LDS rotation (48 KB),
// counted vmcnt + raw s_barrier -> loads for tile kt+2 stay in flight across
// barriers. Staging: waves 0,1 -> A; waves 2,3 -> B. XOR-swizzled both sides.
// Correctness ledger: buffer (kt+2)%3's last readers ran in iter kt-1
// (before this iter's barrier); each wave's vmcnt(4) before the barrier
// proves its tile-kt loads landed -> after barrier all waves' loads landed.
template <typename EPI>
__device__ __forceinline__ void gemm_pipe_core(const bf16* __restrict__ A,
                                               const bf16* __restrict__ B,
                                               int bm, int bn, bf16* As, bf16* Bs,
                                               f32x4 (&acc)[4][4]) {
  const int t = threadIdx.x, wv = t >> 6, ln = t & 63;
  const int wm = wv >> 1, wn = wv & 1;
  const int q = ln >> 4, r = ln & 15;

  // staging geometry (per-lane constants)
  const bf16* G = (wv < 2) ? A : B;
  const int gbase = ((wv < 2) ? bm : bn) * 128;
  const int srow0 = (wv & 1) * 64 + (ln >> 2);         // chunk0 row
  const int slotp = (ln & 3) ^ ((ln >> 2) & 3) ^ ((ln >> 4) & 3);
  const char* gsrc = (const char*)G + ((size_t)(gbase + srow0) * 512) * 2 + slotp * 16;
  bf16* lbase = (wv < 2) ? As : Bs;
  const int lchunk0 = (wv & 1) * 4;                    // chunks 0..3 or 4..7

  // read-side swizzle (per-lane constant)
  const int swzr = (r & 3) ^ ((r >> 2) & 3);

#define STAGE(kt, b)                                                          \
  {                                                                           \
    const char* gk = gsrc + (size_t)(kt) * 64;                                \
    _Pragma("unroll")                                                         \
    for (int i = 0; i < 4; ++i)                                               \
      gll16(gk + (size_t)i * 16 * 1024, lbase + (b) * 4096 + (lchunk0 + i) * 512); \
  }

#define COMPUTE(b)                                                            \
  {                                                                           \
    bf16x8 af[4], bfr[4];                                                     \
    _Pragma("unroll")                                                         \
    for (int m = 0; m < 4; ++m)                                               \
      af[m] = *(const bf16x8*)(As + (b) * 4096 +                              \
                               (wm * 64 + m * 16 + r) * 32 + (q ^ swzr) * 8); \
    _Pragma("unroll")                                                         \
    for (int n = 0; n < 4; ++n)                                               \
      bfr[n] = *(const bf16x8*)(Bs + (b) * 4096 +                             \
                                (wn * 64 + n * 16 + r) * 32 + (q ^ swzr) * 8);\
    _Pragma("unroll")                                                         \
    for (int m = 0; m < 4; ++m) {                                             \
      _Pragma("unroll")                                                       \
      for (int n = 0; n < 4; ++n) acc[m][n] = MFMA(af[m], bfr[n], acc[m][n]); \
    }                                                                         \
  }

  // prologue: tiles 0,1 in flight
  STAGE(0, 0);
  STAGE(1, 1);
  int b = 0;
  for (int kt = 0; kt < 15; ++kt) {
    asm volatile("s_waitcnt vmcnt(4)" ::: "memory");
    __builtin_amdgcn_s_barrier();
    if (kt < 14) {
      const int b2 = (kt + 2) % 3;
      STAGE(kt + 2, b2);
    }
    COMPUTE(b);
    b = (b + 1) % 3;
  }
  asm volatile("s_waitcnt vmcnt(0)" ::: "memory");
  __builtin_amdgcn_s_barrier();
  COMPUTE(b);
#undef STAGE
#undef COMPUTE
}

struct EpiNull {};

// Merged QKV projection, pipelined. 1536 blocks.
__global__ __launch_bounds__(256, 3) void k_gemmQKV(const bf16* __restrict__ qb,
                                                    const bf16* __restrict__ ctxb,
                                                    const bf16* __restrict__ wib,
                                                    const float* __restrict__ in_b,
                                                    bf16* __restrict__ Qa,
                                                    bf16* __restrict__ Ka,
                                                    bf16* __restrict__ Vt) {
  __shared__ bf16 As[3 * 4096];
  __shared__ bf16 Bs[3 * 4096];
  const int t = threadIdx.x, wv = t >> 6, ln = t & 63;
  const int bm = blockIdx.x, bny = blockIdx.y;
  const bool isQ = (bny < 4);
  const int bn = isQ ? bny : bny - 4;
  const bf16* A = isQ ? qb : ctxb;
  const bf16* B = isQ ? wib : wib + 512 * 512;
  const float* bias = isQ ? in_b : in_b + 512;
  const int wm = wv >> 1, wn = wv & 1;
  const int q = ln >> 4, r = ln & 15;
  f32x4 acc[4][4] = {};

  gemm_pipe_core<EpiNull>(A, B, bm, bn, As, Bs, acc);

  const int r0 = bm * 128 + wm * 64 + q * 4;
  const int c0 = bn * 128 + wn * 64 + r;
  #pragma unroll
  for (int m = 0; m < 4; ++m) {
    const int rg0 = r0 + m * 16;
    const int li = rg0 >> 8;
    #pragma unroll
    for (int n = 0; n < 4; ++n) {
      const int cg = c0 + n * 16;
      const float bv = bias[cg];
      if (isQ) {
        #pragma unroll
        for (int j = 0; j < 4; ++j) {
          int sp = (rg0 + j) & 255;
          Qa[(((size_t)li * 8 + (cg >> 6)) * 256 + sp) * 64 + (cg & 63)] =
              (bf16)(acc[m][n][j] + bv);
        }
      } else if (cg < 512) {
        #pragma unroll
        for (int j = 0; j < 4; ++j) {
          int sp = (rg0 + j) & 255;
          Ka[(((size_t)li * 8 + (cg >> 6)) * 256 + sp) * 64 + (cg & 63)] =
              (bf16)(acc[m][n][j] + bv);
        }
      } else {
        const int e = cg - 512, hh = e >> 6, d = e & 63;
        const int sp = rg0 & 255;
        bf16x4 pk;
        #pragma unroll
        for (int j = 0; j < 4; ++j) pk[j] = (bf16)(acc[m][n][j] + bv);
        *(bf16x4*)(&Vt[(((size_t)li * 8 + hh) * 64 + d) * 256 + sp]) = pk;
      }
    }
  }
}

// Out projection GEMM, pipelined.
__global__ __launch_bounds__(256, 3) void k_gemmO(const bf16* __restrict__ A,
                                                  const bf16* __restrict__ B,
                                                  const float* __restrict__ bias,
                                                  bf16* __restrict__ O0) {
  __shared__ bf16 As[3 * 4096];
  __shared__ bf16 Bs[3 * 4096];
  const int t = threadIdx.x, wv = t >> 6, ln = t & 63;
  const int bm = blockIdx.x, bn = blockIdx.y;
  const int wm = wv >> 1, wn = wv & 1;
  const int q = ln >> 4, r = ln & 15;
  f32x4 acc[4][4] = {};

  gemm_pipe_core<EpiNull>(A, B, bm, bn, As, Bs, acc);

  const int r0 = bm * 128 + wm * 64 + q * 4;
  const int c0 = bn * 128 + wn * 64 + r;
  #pragma unroll
  for (int m = 0; m < 4; ++m) {
    const int rg0 = r0 + m * 16;
    #pragma unroll
    for (int n = 0; n < 4; ++n) {
      const int cg = c0 + n * 16;
      const float bv = bias[cg];
      #pragma unroll
      for (int j = 0; j < 4; ++j)
        O0[(size_t)(rg0 + j) * 512 + cg] = (bf16)(acc[m][n][j] + bv);
    }
  }
}

// ---------------------------------------------------------------------------
// Attention per (l,h,s-tile 64), flash over t in 2 halves of 128.
// r10 structure (measured 43.0 us).
__global__ __launch_bounds__(256, 4) void k_attn(const bf16* __restrict__ Qa,
                                                 const bf16* __restrict__ Ka,
                                                 const bf16* __restrict__ Vt,
                                                 bf16* __restrict__ Oa) {
  __shared__ bf16 Ks[128][68];
  __shared__ bf16 Ps[64][132];
  __shared__ float sfl[64];
  __shared__ float rrs[64];

  const int t = threadIdx.x, wv = t >> 6, ln = t & 63;
  const int q = ln >> 4, r = ln & 15;
  const int bid = blockIdx.x;
  const int st = (bid >> 3) & 3;
  const int lh = (bid & 7) | ((bid >> 5) << 3);
  const int s0 = st * 64;
  const size_t base = (size_t)lh * (256 * 64);
  const bf16* Qlh = Qa + base;
  const bf16* Klh = Ka + base;
  const bf16* Vlh = Vt + base;

  const float SC = 0.125f * 1.4426950408889634f;

  bf16x8 aq[2];
  #pragma unroll
  for (int ks = 0; ks < 2; ++ks)
    aq[ks] = *(const bf16x8*)(Qlh + (size_t)(s0 + wv * 16 + r) * 64 + ks * 32 + q * 8);

  const int krow = t >> 1, khf = (t & 1) * 32;
  {
    bf16x8 kst0[4];
    #pragma unroll
    for (int i = 0; i < 4; ++i)
      kst0[i] = *(const bf16x8*)(Klh + (size_t)krow * 64 + khf + i * 8);
    #pragma unroll
    for (int i = 0; i < 4; ++i) *(bf16x8*)(&Ks[krow][khf + i * 8]) = kst0[i];
  }
  __syncthreads();

  f32x4 ao[4] = {};
  float m4[4], l4[4];
  f32x4 acc[8];

  // ================= half 0 =================
  #pragma unroll
  for (int n = 0; n < 8; ++n) acc[n] = (f32x4){0.f, 0.f, 0.f, 0.f};
  __builtin_amdgcn_s_setprio(1);
  #pragma unroll
  for (int n = 0; n < 8; ++n) {
    bf16x8 b0 = *(const bf16x8*)(&Ks[n * 16 + r][q * 8]);
    bf16x8 b1 = *(const bf16x8*)(&Ks[n * 16 + r][32 + q * 8]);
    acc[n] = MFMA(aq[0], b0, acc[n]);
    acc[n] = MFMA(aq[1], b1, acc[n]);
  }
  __builtin_amdgcn_s_setprio(0);

  bf16x8 bv[4];
  #pragma unroll
  for (int ks = 0; ks < 4; ++ks)
    bv[ks] = *(const bf16x8*)(Vlh + (size_t)(wv * 16 + r) * 256 + ks * 32 + q * 8);
  bf16x8 kst[4];
  #pragma unroll
  for (int i = 0; i < 4; ++i)
    kst[i] = *(const bf16x8*)(Klh + (size_t)(128 + krow) * 64 + khf + i * 8);

  #pragma unroll
  for (int j = 0; j < 4; ++j) {
    float mx = acc[0][j];
    #pragma unroll
    for (int n = 1; n < 8; ++n) mx = fmaxf(mx, acc[n][j]);
    #pragma unroll
    for (int off = 1; off < 16; off <<= 1) mx = fmaxf(mx, __shfl_xor(mx, off));
    m4[j] = mx;
    const float ms = mx * SC;
    float sm = 0.f;
    #pragma unroll
    for (int n = 0; n < 8; ++n) {
      float p = exp2f(acc[n][j] * SC - ms);
      acc[n][j] = p;
      sm += p;
    }
    #pragma unroll
    for (int off = 1; off < 16; off <<= 1) sm += __shfl_xor(sm, off);
    l4[j] = sm;
    const int row = wv * 16 + q * 4 + j;
    #pragma unroll
    for (int n = 0; n < 8; ++n) Ps[row][n * 16 + r] = (bf16)acc[n][j];
  }
  __syncthreads();

  #pragma unroll
  for (int i = 0; i < 4; ++i) *(bf16x8*)(&Ks[krow][khf + i * 8]) = kst[i];
  __builtin_amdgcn_s_setprio(1);
  #pragma unroll
  for (int ks = 0; ks < 4; ++ks) {
    #pragma unroll
    for (int m = 0; m < 4; ++m) {
      bf16x8 ap = *(const bf16x8*)(&Ps[m * 16 + r][ks * 32 + q * 8]);
      ao[m] = MFMA(ap, bv[ks], ao[m]);
    }
  }
  __builtin_amdgcn_s_setprio(0);
  __syncthreads();

  // ================= half 1 =================
  #pragma unroll
  for (int n = 0; n < 8; ++n) acc[n] = (f32x4){0.f, 0.f, 0.f, 0.f};
  __builtin_amdgcn_s_setprio(1);
  #pragma unroll
  for (int n = 0; n < 8; ++n) {
    bf16x8 b0 = *(const bf16x8*)(&Ks[n * 16 + r][q * 8]);
    bf16x8 b1 = *(const bf16x8*)(&Ks[n * 16 + r][32 + q * 8]);
    acc[n] = MFMA(aq[0], b0, acc[n]);
    acc[n] = MFMA(aq[1], b1, acc[n]);
  }
  __builtin_amdgcn_s_setprio(0);
  #pragma unroll
  for (int ks = 0; ks < 4; ++ks)
    bv[ks] = *(const bf16x8*)(Vlh + (size_t)(wv * 16 + r) * 256 + 128 + ks * 32 + q * 8);

  float sf4[4], rr4[4];
  #pragma unroll
  for (int j = 0; j < 4; ++j) {
    float mx = acc[0][j];
    #pragma unroll
    for (int n = 1; n < 8; ++n) mx = fmaxf(mx, acc[n][j]);
    #pragma unroll
    for (int off = 1; off < 16; off <<= 1) mx = fmaxf(mx, __shfl_xor(mx, off));
    const float mn = fmaxf(m4[j], mx);
    const float sf = exp2f((m4[j] - mn) * SC);
    const float ms = mn * SC;
    float sm = 0.f;
    #pragma unroll
    for (int n = 0; n < 8; ++n) {
      float p = exp2f(acc[n][j] * SC - ms);
      acc[n][j] = p;
      sm += p;
    }
    #pragma unroll
    for (int off = 1; off < 16; off <<= 1) sm += __shfl_xor(sm, off);
    sf4[j] = sf;
    rr4[j] = 1.f / (l4[j] * sf + sm);
    const int row = wv * 16 + q * 4 + j;
    #pragma unroll
    for (int n = 0; n < 8; ++n) Ps[row][n * 16 + r] = (bf16)acc[n][j];
  }
  if (r == 0) {
    *(f32x4*)(&sfl[wv * 16 + q * 4]) = (f32x4){sf4[0], sf4[1], sf4[2], sf4[3]};
    *(f32x4*)(&rrs[wv * 16 + q * 4]) = (f32x4){rr4[0], rr4[1], rr4[2], rr4[3]};
  }
  __syncthreads();

  #pragma unroll
  for (int m = 0; m < 4; ++m) {
    f32x4 sv = *(const f32x4*)(&sfl[m * 16 + q * 4]);
    #pragma unroll
    for (int j = 0; j < 4; ++j) ao[m][j] *= sv[j];
  }
  __builtin_amdgcn_s_setprio(1);
  #pragma unroll
  for (int ks = 0; ks < 4; ++ks) {
    #pragma unroll
    for (int m = 0; m < 4; ++m) {
      bf16x8 ap = *(const bf16x8*)(&Ps[m * 16 + r][ks * 32 + q * 8]);
      ao[m] = MFMA(ap, bv[ks], ao[m]);
    }
  }
  __builtin_amdgcn_s_setprio(0);

  float(*FS)[68] = (float(*)[68])(&Ks[0][0]);
  #pragma unroll
  for (int m = 0; m < 4; ++m) {
    f32x4 rv = *(const f32x4*)(&rrs[m * 16 + q * 4]);
    #pragma unroll
    for (int j = 0; j < 4; ++j)
      FS[m * 16 + q * 4 + j][wv * 16 + r] = ao[m][j] * rv[j];
  }
  __syncthreads();

  {
    const int row = t >> 2, qq = t & 3;
    const float* srcp = &FS[row][qq * 16];
    bf16x8 o0, o1;
    #pragma unroll
    for (int i = 0; i < 8; ++i) o0[i] = (bf16)srcp[i];
    #pragma unroll
    for (int i = 0; i < 8; ++i) o1[i] = (bf16)srcp[8 + i];
    bf16* dst = Oa + ((size_t)(lh >> 3) * 256 + s0 + row) * 512 + (lh & 7) * 64 + qq * 16;
    *(bf16x8*)(dst) = o0;
    *(bf16x8*)(dst + 8) = o1;
  }
}

// ---------------------------------------------------------------------------
__global__ void k_orelay(const bf16* __restrict__ o_tmp, float* __restrict__ out) {
  __shared__ bf16 buf[64][130];
  const int hy = blockIdx.x, py = blockIdx.y, e0 = blockIdx.z * 64, t = threadIdx.x;
  #pragma unroll
  for (int i = 0; i < 32; ++i) {
    int flat = i * 256 + t;
    int r = flat >> 6, e = flat & 63;
    int px = r >> 4, hx = r & 15;
    buf[e][hx * 8 + px] =
        o_tmp[((size_t)(py * 8 + px) * 256 + hy * 16 + hx) * 512 + e0 + e];
  }
  __syncthreads();
  const int Y = hy * 8 + py;
  #pragma unroll
  for (int i = 0; i < 32; ++i) {
    int flat = i * 256 + t;
    int e = flat >> 7, X = flat & 127;
    out[(size_t)(e0 + e) * 16384 + (size_t)Y * 128 + X] = (float)buf[e][X];
  }
}

// ---------------------------------------------------------------------------
extern "C" void kernel_launch(void* const* d_in, const int* in_sizes, int n_in,
                              void* d_out, int out_size, void* d_ws, size_t ws_size,
                              hipStream_t stream) {
  const float* x     = (const float*)d_in[0];
  const float* ln_w  = (const float*)d_in[1];
  const float* ln_b  = (const float*)d_in[2];
  const float* mix_w = (const float*)d_in[3];
  const float* mix_b = (const float*)d_in[4];
  const float* in_w  = (const float*)d_in[5];
  const float* in_b  = (const float*)d_in[6];
  const float* out_w = (const float*)d_in[7];
  const float* out_b = (const float*)d_in[8];
  float* out = (float*)d_out;
  char* ws = (char*)d_ws;

  const size_t MB = 1u << 20;
  float* xp2t = (float*)(ws);
  bf16* qb    = (bf16*)(ws + 8 * MB);
  bf16* Tn    = (bf16*)(ws + 24 * MB);
  bf16* ctxb  = (bf16*)(ws + 40 * MB);
  bf16* Qa    = (bf16*)(ws + 56 * MB);
  bf16* Ka    = (bf16*)(ws);
  bf16* Vt    = (bf16*)(ws + 16 * MB);
  bf16* oatt  = (bf16*)(ws + 32 * MB);
  bf16* otmp  = (bf16*)(ws + 48 * MB);
  bf16* wib   = (bf16*)(ws + 72 * MB);
  bf16* wob   = (bf16*)(ws + 72 * MB + 1572864);

  k_wconv<<<1024, 256, 0, stream>>>(in_w, out_w, wib, wob);
  k_pq<<<dim3(64, 8), 256, 0, stream>>>(x, xp2t, qb);
  k_ln<<<dim3(256, 4), 512, 0, stream>>>(xp2t, ln_w, ln_b, Tn);
  k_mix<<<dim3(256, 2), 256, 0, stream>>>(Tn, mix_w, mix_b, ctxb);
  k_gemmQKV<<<dim3(128, 12), 256, 0, stream>>>(qb, ctxb, wib, in_b, Qa, Ka, Vt);
  k_attn<<<2048, 256, 0, stream>>>(Qa, Ka, Vt, oatt);
  k_gemmO<<<dim3(128, 4), 256, 0, stream>>>(oatt, wob, out_b, otmp);
  k_orelay<<<dim3(16, 8, 8), 256, 0, stream>>>(otmp, out);
}

// Round 16
// 132.798 us; speedup vs baseline: 1.0438x; 1.0438x over previous
//
#include <hip/hip_runtime.h>

// ---------------------------------------------------------------------------
// LargeWindowAttention on MI355X (gfx950)  — FINAL (r12 configuration)
// pq(fused pool+q-relayout) -> ln -> mix(MFMA) -> merged QKV GEMM ->
// batched window attention (flash 2-half, reg-staged K->LDS, V prefetch,
// Ps handoff, setprio) -> out GEMM -> relayout.   Measured: 133.2 us.
// ---------------------------------------------------------------------------

typedef __bf16 bf16;
typedef __bf16 bf16x2 __attribute__((ext_vector_type(2)));
typedef __bf16 bf16x4 __attribute__((ext_vector_type(4)));
typedef __bf16 bf16x8 __attribute__((ext_vector_type(8)));
typedef float f32x4 __attribute__((ext_vector_type(4)));

#define MFMA(a, b, c) __builtin_amdgcn_mfma_f32_16x16x32_bf16(a, b, c, 0, 0, 0)

__device__ __forceinline__ void gll16(const void* g, void* l) {
  __builtin_amdgcn_global_load_lds((const __attribute__((address_space(1))) void*)g,
                                   (__attribute__((address_space(3))) void*)l, 16, 0, 0);
}

// ---------------------------------------------------------------------------
__global__ void k_wconv(const float* __restrict__ in_w, const float* __restrict__ out_w,
                        bf16* __restrict__ wib, bf16* __restrict__ wob) {
  int i = blockIdx.x * blockDim.x + threadIdx.x;
  const int n1 = (1536 * 512) / 4;
  float4 v;
  bf16* dst;
  if (i < n1) { v = ((const float4*)in_w)[i];      dst = wib + (size_t)i * 4; }
  else        { v = ((const float4*)out_w)[i - n1]; dst = wob + (size_t)(i - n1) * 4; }
  dst[0] = (bf16)v.x; dst[1] = (bf16)v.y; dst[2] = (bf16)v.z; dst[3] = (bf16)v.w;
}

// ---------------------------------------------------------------------------
// Fused: read x once -> pooled xp2t[y2][x2][c] fp32 + q relayout bf16.
__global__ __launch_bounds__(256) void k_pq(const float* __restrict__ x,
                                            float* __restrict__ xp2t,
                                            bf16* __restrict__ qb) {
  __shared__ float xs[2][64][133];
  const int y2 = blockIdx.x, c0 = blockIdx.y * 64, t = threadIdx.x;
  #pragma unroll
  for (int it = 0; it < 16; ++it) {
    int flat = it * 256 + t;
    int ci = flat >> 6, rest = flat & 63;
    int yb = rest >> 5, xq = rest & 31;
    float4 v = *(const float4*)(x + (size_t)(c0 + ci) * 16384 +
                                (size_t)(2 * y2 + yb) * 128 + xq * 4);
    float* d = &xs[yb][ci][xq * 4];
    d[0] = v.x; d[1] = v.y; d[2] = v.z; d[3] = v.w;
  }
  __syncthreads();
  #pragma unroll
  for (int it = 0; it < 16; ++it) {
    int flat = it * 256 + t;
    int x2 = flat >> 6, ci = flat & 63;
    float s = xs[0][ci][2 * x2] + xs[0][ci][2 * x2 + 1] +
              xs[1][ci][2 * x2] + xs[1][ci][2 * x2 + 1];
    xp2t[(size_t)(y2 * 64 + x2) * 512 + c0 + ci] = 0.25f * s;
  }
  #pragma unroll
  for (int yb = 0; yb < 2; ++yb) {
    const int Y = 2 * y2 + yb;
    const int hy = Y >> 3, py = Y & 7;
    #pragma unroll
    for (int it = 0; it < 32; ++it) {
      int flat = it * 256 + t;
      int X = flat >> 6, ci = flat & 63;
      int l = py * 8 + (X & 7), s = hy * 16 + (X >> 3);
      qb[((size_t)l * 256 + s) * 512 + c0 + ci] = (bf16)xs[yb][ci][X];
    }
  }
}

// ---------------------------------------------------------------------------
__global__ __launch_bounds__(512) void k_ln(const float* __restrict__ xp2t,
                                            const float* __restrict__ lnw,
                                            const float* __restrict__ lnb,
                                            bf16* __restrict__ T) {
  __shared__ bf16 Tt[512][24];
  const int s = blockIdx.x, qt = blockIdx.y;
  const int wy = s >> 4, wx = s & 15;
  const int t = threadIdx.x, wv = t >> 6, ln = t & 63;

  float wl[8], bl[8];
  #pragma unroll
  for (int k = 0; k < 8; ++k) { wl[k] = lnw[k * 64 + ln]; bl[k] = lnb[k * 64 + ln]; }

  float v[2][8], mu_[2], rs_[2];
  #pragma unroll
  for (int p = 0; p < 2; ++p) {
    const int l = qt * 16 + wv * 2 + p;
    const int py = l >> 3, px = l & 7;
    const int y2 = wy * 4 - 2 + py, x2 = wx * 4 - 2 + px;
    const bool inb = (y2 >= 0) && (y2 < 64) && (x2 >= 0) && (x2 < 64);
    const float* src = xp2t + (size_t)(y2 * 64 + x2) * 512;
    float sum = 0.f, ssq = 0.f;
    #pragma unroll
    for (int k = 0; k < 8; ++k) {
      float xv = 0.f;
      if (inb) xv = src[k * 64 + ln];
      v[p][k] = xv; sum += xv; ssq += xv * xv;
    }
    #pragma unroll
    for (int off = 1; off < 64; off <<= 1) {
      sum += __shfl_xor(sum, off);
      ssq += __shfl_xor(ssq, off);
    }
    float mu = sum * (1.f / 512.f);
    mu_[p] = mu;
    rs_[p] = rsqrtf(ssq * (1.f / 512.f) - mu * mu + 1e-6f);
  }
  #pragma unroll
  for (int k = 0; k < 8; ++k) {
    const int c = k * 64 + ln;
    bf16x2 u;
    u.x = (bf16)((v[0][k] - mu_[0]) * rs_[0] * wl[k] + bl[k]);
    u.y = (bf16)((v[1][k] - mu_[1]) * rs_[1] * wl[k] + bl[k]);
    *(bf16x2*)(&Tt[c][wv * 2]) = u;
  }
  __syncthreads();
  #pragma unroll
  for (int it = 0; it < 2; ++it) {
    int flat = it * 512 + t;
    int c = flat >> 1, ch = flat & 1;
    bf16x8 u = *(const bf16x8*)(&Tt[c][ch * 8]);
    *(bf16x8*)(T + ((size_t)s * 512 + c) * 64 + qt * 16 + ch * 8) = u;
  }
}

// ---------------------------------------------------------------------------
__global__ __launch_bounds__(256) void k_mix(const bf16* __restrict__ T,
                                             const float* __restrict__ mix_w,
                                             const float* __restrict__ mix_b,
                                             bf16* __restrict__ ctx) {
  const int t = threadIdx.x, wv = t >> 6, ln = t & 63;
  const int s = blockIdx.x, hg = blockIdx.y;
  const int h = hg * 4 + wv;
  const int q = ln >> 4, r = ln & 15;

  bf16x8 a[4][2];
  #pragma unroll
  for (int m = 0; m < 4; ++m) {
    #pragma unroll
    for (int ks = 0; ks < 2; ++ks) {
      const int rm = m * 16 + r;
      const float* wsrc = mix_w + ((size_t)h * 64 + rm) * 64 + ks * 32 + q * 8;
      bf16x8 pk;
      #pragma unroll
      for (int e = 0; e < 8; ++e) {
        int l = ks * 32 + q * 8 + e;
        float w = wsrc[e] + (rm == l ? 1.f : 0.f);
        pk[e] = (bf16)w;
      }
      a[m][ks] = pk;
    }
  }
  const bf16* Tb = T + ((size_t)s * 512 + h * 64) * 64;
  bf16x8 b[4][2];
  #pragma unroll
  for (int n = 0; n < 4; ++n) {
    #pragma unroll
    for (int ks = 0; ks < 2; ++ks)
      b[n][ks] = *(const bf16x8*)(Tb + (size_t)(n * 16 + r) * 64 + ks * 32 + q * 8);
  }
  f32x4 acc[4][4] = {};
  #pragma unroll
  for (int ks = 0; ks < 2; ++ks) {
    #pragma unroll
    for (int m = 0; m < 4; ++m) {
      #pragma unroll
      for (int n = 0; n < 4; ++n) acc[m][n] = MFMA(a[m][ks], b[n][ks], acc[m][n]);
    }
  }
  #pragma unroll
  for (int m = 0; m < 4; ++m) {
    #pragma unroll
    for (int j = 0; j < 4; ++j) {
      const int rm = m * 16 + q * 4 + j;
      const float bias = mix_b[h * 64 + rm];
      #pragma unroll
      for (int n = 0; n < 4; ++n)
        ctx[((size_t)rm * 256 + s) * 512 + h * 64 + n * 16 + r] =
            (bf16)(acc[m][n][j] + bias);
    }
  }
}

// ---------------------------------------------------------------------------
// Merged QKV projection: one dispatch, 1536 blocks. 128x128 tile, BK=64,
// gll16 staging with XOR-swizzled source (read side same XOR, conflict-free).
__global__ __launch_bounds__(256, 4) void k_gemmQKV(const bf16* __restrict__ qb,
                                                    const bf16* __restrict__ ctxb,
                                                    const bf16* __restrict__ wib,
                                                    const float* __restrict__ in_b,
                                                    bf16* __restrict__ Qa,
                                                    bf16* __restrict__ Ka,
                                                    bf16* __restrict__ Vt) {
  __shared__ bf16 As[8192];
  __shared__ bf16 Bs[8192];
  const int t = threadIdx.x, wv = t >> 6, ln = t & 63;
  const int bm = blockIdx.x, bny = blockIdx.y;
  const bool isQ = (bny < 4);
  const int bn = isQ ? bny : bny - 4;
  const bf16* A = isQ ? qb : ctxb;
  const bf16* B = isQ ? wib : wib + 512 * 512;
  const float* bias = isQ ? in_b : in_b + 512;
  const int wm = wv >> 1, wn = wv & 1;
  const int q = ln >> 4, r = ln & 15;
  f32x4 acc[4][4] = {};

  const int srow = wv * 8 + (ln >> 3);
  const int swzc = (ln & 7) ^ (ln >> 3);
  const char* ga = (const char*)A + ((size_t)(bm * 128 + srow) * 512) * 2 + swzc * 16;
  const char* gb = (const char*)B + ((size_t)(bn * 128 + srow) * 512) * 2 + swzc * 16;

  for (int k0 = 0; k0 < 512; k0 += 64) {
    #pragma unroll
    for (int i = 0; i < 4; ++i) {
      gll16(ga + (size_t)i * 32 * 1024 + k0 * 2, As + i * 2048 + wv * 512);
      gll16(gb + (size_t)i * 32 * 1024 + k0 * 2, Bs + i * 2048 + wv * 512);
    }
    __syncthreads();
    #pragma unroll
    for (int ks = 0; ks < 2; ++ks) {
      bf16x8 af[4], bfr[4];
      #pragma unroll
      for (int m = 0; m < 4; ++m)
        af[m] = *(const bf16x8*)(As + (wm * 64 + m * 16 + r) * 64 +
                                 (((ks * 4 + q) ^ (r & 7)) * 8));
      #pragma unroll
      for (int n = 0; n < 4; ++n)
        bfr[n] = *(const bf16x8*)(Bs + (wn * 64 + n * 16 + r) * 64 +
                                  (((ks * 4 + q) ^ (r & 7)) * 8));
      #pragma unroll
      for (int m = 0; m < 4; ++m) {
        #pragma unroll
        for (int n = 0; n < 4; ++n) acc[m][n] = MFMA(af[m], bfr[n], acc[m][n]);
      }
    }
    __syncthreads();
  }

  const int r0 = bm * 128 + wm * 64 + q * 4;
  const int c0 = bn * 128 + wn * 64 + r;
  #pragma unroll
  for (int m = 0; m < 4; ++m) {
    const int rg0 = r0 + m * 16;
    const int li = rg0 >> 8;
    #pragma unroll
    for (int n = 0; n < 4; ++n) {
      const int cg = c0 + n * 16;
      const float bv = bias[cg];
      if (isQ) {
        #pragma unroll
        for (int j = 0; j < 4; ++j) {
          int sp = (rg0 + j) & 255;
          Qa[(((size_t)li * 8 + (cg >> 6)) * 256 + sp) * 64 + (cg & 63)] =
              (bf16)(acc[m][n][j] + bv);
        }
      } else if (cg < 512) {
        #pragma unroll
        for (int j = 0; j < 4; ++j) {
          int sp = (rg0 + j) & 255;
          Ka[(((size_t)li * 8 + (cg >> 6)) * 256 + sp) * 64 + (cg & 63)] =
              (bf16)(acc[m][n][j] + bv);
        }
      } else {
        const int e = cg - 512, hh = e >> 6, d = e & 63;
        const int sp = rg0 & 255;
        bf16x4 pk;
        #pragma unroll
        for (int j = 0; j < 4; ++j) pk[j] = (bf16)(acc[m][n][j] + bv);
        *(bf16x4*)(&Vt[(((size_t)li * 8 + hh) * 64 + d) * 256 + sp]) = pk;
      }
    }
  }
}

// ---------------------------------------------------------------------------
// Out projection GEMM.
__global__ __launch_bounds__(256, 4) void k_gemmO(const bf16* __restrict__ A,
                                                  const bf16* __restrict__ B,
                                                  const float* __restrict__ bias,
                                                  bf16* __restrict__ O0) {
  __shared__ bf16 As[8192];
  __shared__ bf16 Bs[8192];
  const int t = threadIdx.x, wv = t >> 6, ln = t & 63;
  const int bm = blockIdx.x, bn = blockIdx.y;
  const int wm = wv >> 1, wn = wv & 1;
  const int q = ln >> 4, r = ln & 15;
  f32x4 acc[4][4] = {};

  const int srow = wv * 8 + (ln >> 3);
  const int swzc = (ln & 7) ^ (ln >> 3);
  const char* ga = (const char*)A + ((size_t)(bm * 128 + srow) * 512) * 2 + swzc * 16;
  const char* gb = (const char*)B + ((size_t)(bn * 128 + srow) * 512) * 2 + swzc * 16;

  for (int k0 = 0; k0 < 512; k0 += 64) {
    #pragma unroll
    for (int i = 0; i < 4; ++i) {
      gll16(ga + (size_t)i * 32 * 1024 + k0 * 2, As + i * 2048 + wv * 512);
      gll16(gb + (size_t)i * 32 * 1024 + k0 * 2, Bs + i * 2048 + wv * 512);
    }
    __syncthreads();
    #pragma unroll
    for (int ks = 0; ks < 2; ++ks) {
      bf16x8 af[4], bfr[4];
      #pragma unroll
      for (int m = 0; m < 4; ++m)
        af[m] = *(const bf16x8*)(As + (wm * 64 + m * 16 + r) * 64 +
                                 (((ks * 4 + q) ^ (r & 7)) * 8));
      #pragma unroll
      for (int n = 0; n < 4; ++n)
        bfr[n] = *(const bf16x8*)(Bs + (wn * 64 + n * 16 + r) * 64 +
                                  (((ks * 4 + q) ^ (r & 7)) * 8));
      #pragma unroll
      for (int m = 0; m < 4; ++m) {
        #pragma unroll
        for (int n = 0; n < 4; ++n) acc[m][n] = MFMA(af[m], bfr[n], acc[m][n]);
      }
    }
    __syncthreads();
  }

  const int r0 = bm * 128 + wm * 64 + q * 4;
  const int c0 = bn * 128 + wn * 64 + r;
  #pragma unroll
  for (int m = 0; m < 4; ++m) {
    const int rg0 = r0 + m * 16;
    #pragma unroll
    for (int n = 0; n < 4; ++n) {
      const int cg = c0 + n * 16;
      const float bv = bias[cg];
      #pragma unroll
      for (int j = 0; j < 4; ++j)
        O0[(size_t)(rg0 + j) * 512 + cg] = (bf16)(acc[m][n][j] + bv);
    }
  }
}

// ---------------------------------------------------------------------------
// Attention per (l,h,s-tile 64), flash over t in 2 halves of 128.
// r10 structure (measured 43.0 us): reg-staged K->LDS (prefetch h1 during
// softmax h0, write during PV h0), V prefetched to regs under softmax,
// cross-wave softmax via 16-lane butterflies, Ps LDS handoff, 3 barriers,
// setprio around MFMA clusters.
__global__ __launch_bounds__(256, 4) void k_attn(const bf16* __restrict__ Qa,
                                                 const bf16* __restrict__ Ka,
                                                 const bf16* __restrict__ Vt,
                                                 bf16* __restrict__ Oa) {
  __shared__ bf16 Ks[128][68];   // 17408 B, pitch 136B (dw stride 34 -> ~2-way)
  __shared__ bf16 Ps[64][132];   // 16896 B
  __shared__ float sfl[64];
  __shared__ float rrs[64];

  const int t = threadIdx.x, wv = t >> 6, ln = t & 63;
  const int q = ln >> 4, r = ln & 15;
  const int bid = blockIdx.x;
  const int st = (bid >> 3) & 3;                 // siblings share bid%8 -> XCD
  const int lh = (bid & 7) | ((bid >> 5) << 3);
  const int s0 = st * 64;
  const size_t base = (size_t)lh * (256 * 64);
  const bf16* Qlh = Qa + base;
  const bf16* Klh = Ka + base;
  const bf16* Vlh = Vt + base;

  const float SC = 0.125f * 1.4426950408889634f;

  bf16x8 aq[2];
  #pragma unroll
  for (int ks = 0; ks < 2; ++ks)
    aq[ks] = *(const bf16x8*)(Qlh + (size_t)(s0 + wv * 16 + r) * 64 + ks * 32 + q * 8);

  const int krow = t >> 1, khf = (t & 1) * 32;
  {
    bf16x8 kst0[4];
    #pragma unroll
    for (int i = 0; i < 4; ++i)
      kst0[i] = *(const bf16x8*)(Klh + (size_t)krow * 64 + khf + i * 8);
    #pragma unroll
    for (int i = 0; i < 4; ++i) *(bf16x8*)(&Ks[krow][khf + i * 8]) = kst0[i];
  }
  __syncthreads();

  f32x4 ao[4] = {};
  float m4[4], l4[4];
  f32x4 acc[8];

  // ================= half 0 =================
  #pragma unroll
  for (int n = 0; n < 8; ++n) acc[n] = (f32x4){0.f, 0.f, 0.f, 0.f};
  __builtin_amdgcn_s_setprio(1);
  #pragma unroll
  for (int n = 0; n < 8; ++n) {
    bf16x8 b0 = *(const bf16x8*)(&Ks[n * 16 + r][q * 8]);
    bf16x8 b1 = *(const bf16x8*)(&Ks[n * 16 + r][32 + q * 8]);
    acc[n] = MFMA(aq[0], b0, acc[n]);
    acc[n] = MFMA(aq[1], b1, acc[n]);
  }
  __builtin_amdgcn_s_setprio(0);

  bf16x8 bv[4];
  #pragma unroll
  for (int ks = 0; ks < 4; ++ks)
    bv[ks] = *(const bf16x8*)(Vlh + (size_t)(wv * 16 + r) * 256 + ks * 32 + q * 8);
  bf16x8 kst[4];
  #pragma unroll
  for (int i = 0; i < 4; ++i)
    kst[i] = *(const bf16x8*)(Klh + (size_t)(128 + krow) * 64 + khf + i * 8);

  #pragma unroll
  for (int j = 0; j < 4; ++j) {
    float mx = acc[0][j];
    #pragma unroll
    for (int n = 1; n < 8; ++n) mx = fmaxf(mx, acc[n][j]);
    #pragma unroll
    for (int off = 1; off < 16; off <<= 1) mx = fmaxf(mx, __shfl_xor(mx, off));
    m4[j] = mx;
    const float ms = mx * SC;
    float sm = 0.f;
    #pragma unroll
    for (int n = 0; n < 8; ++n) {
      float p = exp2f(acc[n][j] * SC - ms);
      acc[n][j] = p;
      sm += p;
    }
    #pragma unroll
    for (int off = 1; off < 16; off <<= 1) sm += __shfl_xor(sm, off);
    l4[j] = sm;
    const int row = wv * 16 + q * 4 + j;
    #pragma unroll
    for (int n = 0; n < 8; ++n) Ps[row][n * 16 + r] = (bf16)acc[n][j];
  }
  __syncthreads();

  #pragma unroll
  for (int i = 0; i < 4; ++i) *(bf16x8*)(&Ks[krow][khf + i * 8]) = kst[i];
  __builtin_amdgcn_s_setprio(1);
  #pragma unroll
  for (int ks = 0; ks < 4; ++ks) {
    #pragma unroll
    for (int m = 0; m < 4; ++m) {
      bf16x8 ap = *(const bf16x8*)(&Ps[m * 16 + r][ks * 32 + q * 8]);
      ao[m] = MFMA(ap, bv[ks], ao[m]);
    }
  }
  __builtin_amdgcn_s_setprio(0);
  __syncthreads();

  // ================= half 1 =================
  #pragma unroll
  for (int n = 0; n < 8; ++n) acc[n] = (f32x4){0.f, 0.f, 0.f, 0.f};
  __builtin_amdgcn_s_setprio(1);
  #pragma unroll
  for (int n = 0; n < 8; ++n) {
    bf16x8 b0 = *(const bf16x8*)(&Ks[n * 16 + r][q * 8]);
    bf16x8 b1 = *(const bf16x8*)(&Ks[n * 16 + r][32 + q * 8]);
    acc[n] = MFMA(aq[0], b0, acc[n]);
    acc[n] = MFMA(aq[1], b1, acc[n]);
  }
  __builtin_amdgcn_s_setprio(0);
  #pragma unroll
  for (int ks = 0; ks < 4; ++ks)
    bv[ks] = *(const bf16x8*)(Vlh + (size_t)(wv * 16 + r) * 256 + 128 + ks * 32 + q * 8);

  float sf4[4], rr4[4];
  #pragma unroll
  for (int j = 0; j < 4; ++j) {
    float mx = acc[0][j];
    #pragma unroll
    for (int n = 1; n < 8; ++n) mx = fmaxf(mx, acc[n][j]);
    #pragma unroll
    for (int off = 1; off < 16; off <<= 1) mx = fmaxf(mx, __shfl_xor(mx, off));
    const float mn = fmaxf(m4[j], mx);
    const float sf = exp2f((m4[j] - mn) * SC);
    const float ms = mn * SC;
    float sm = 0.f;
    #pragma unroll
    for (int n = 0; n < 8; ++n) {
      float p = exp2f(acc[n][j] * SC - ms);
      acc[n][j] = p;
      sm += p;
    }
    #pragma unroll
    for (int off = 1; off < 16; off <<= 1) sm += __shfl_xor(sm, off);
    sf4[j] = sf;
    rr4[j] = 1.f / (l4[j] * sf + sm);
    const int row = wv * 16 + q * 4 + j;
    #pragma unroll
    for (int n = 0; n < 8; ++n) Ps[row][n * 16 + r] = (bf16)acc[n][j];
  }
  if (r == 0) {
    *(f32x4*)(&sfl[wv * 16 + q * 4]) = (f32x4){sf4[0], sf4[1], sf4[2], sf4[3]};
    *(f32x4*)(&rrs[wv * 16 + q * 4]) = (f32x4){rr4[0], rr4[1], rr4[2], rr4[3]};
  }
  __syncthreads();

  #pragma unroll
  for (int m = 0; m < 4; ++m) {
    f32x4 sv = *(const f32x4*)(&sfl[m * 16 + q * 4]);
    #pragma unroll
    for (int j = 0; j < 4; ++j) ao[m][j] *= sv[j];
  }
  __builtin_amdgcn_s_setprio(1);
  #pragma unroll
  for (int ks = 0; ks < 4; ++ks) {
    #pragma unroll
    for (int m = 0; m < 4; ++m) {
      bf16x8 ap = *(const bf16x8*)(&Ps[m * 16 + r][ks * 32 + q * 8]);
      ao[m] = MFMA(ap, bv[ks], ao[m]);
    }
  }
  __builtin_amdgcn_s_setprio(0);

  float(*FS)[68] = (float(*)[68])(&Ks[0][0]);
  #pragma unroll
  for (int m = 0; m < 4; ++m) {
    f32x4 rv = *(const f32x4*)(&rrs[m * 16 + q * 4]);
    #pragma unroll
    for (int j = 0; j < 4; ++j)
      FS[m * 16 + q * 4 + j][wv * 16 + r] = ao[m][j] * rv[j];
  }
  __syncthreads();

  {
    const int row = t >> 2, qq = t & 3;
    const float* srcp = &FS[row][qq * 16];
    bf16x8 o0, o1;
    #pragma unroll
    for (int i = 0; i < 8; ++i) o0[i] = (bf16)srcp[i];
    #pragma unroll
    for (int i = 0; i < 8; ++i) o1[i] = (bf16)srcp[8 + i];
    bf16* dst = Oa + ((size_t)(lh >> 3) * 256 + s0 + row) * 512 + (lh & 7) * 64 + qq * 16;
    *(bf16x8*)(dst) = o0;
    *(bf16x8*)(dst + 8) = o1;
  }
}

// ---------------------------------------------------------------------------
__global__ void k_orelay(const bf16* __restrict__ o_tmp, float* __restrict__ out) {
  __shared__ bf16 buf[64][130];
  const int hy = blockIdx.x, py = blockIdx.y, e0 = blockIdx.z * 64, t = threadIdx.x;
  #pragma unroll
  for (int i = 0; i < 32; ++i) {
    int flat = i * 256 + t;
    int r = flat >> 6, e = flat & 63;
    int px = r >> 4, hx = r & 15;
    buf[e][hx * 8 + px] =
        o_tmp[((size_t)(py * 8 + px) * 256 + hy * 16 + hx) * 512 + e0 + e];
  }
  __syncthreads();
  const int Y = hy * 8 + py;
  #pragma unroll
  for (int i = 0; i < 32; ++i) {
    int flat = i * 256 + t;
    int e = flat >> 7, X = flat & 127;
    out[(size_t)(e0 + e) * 16384 + (size_t)Y * 128 + X] = (float)buf[e][X];
  }
}

// ---------------------------------------------------------------------------
extern "C" void kernel_launch(void* const* d_in, const int* in_sizes, int n_in,
                              void* d_out, int out_size, void* d_ws, size_t ws_size,
                              hipStream_t stream) {
  const float* x     = (const float*)d_in[0];
  const float* ln_w  = (const float*)d_in[1];
  const float* ln_b  = (const float*)d_in[2];
  const float* mix_w = (const float*)d_in[3];
  const float* mix_b = (const float*)d_in[4];
  const float* in_w  = (const float*)d_in[5];
  const float* in_b  = (const float*)d_in[6];
  const float* out_w = (const float*)d_in[7];
  const float* out_b = (const float*)d_in[8];
  float* out = (float*)d_out;
  char* ws = (char*)d_ws;

  const size_t MB = 1u << 20;
  float* xp2t = (float*)(ws);                    // [0,8)   pq -> ln
  bf16* qb    = (bf16*)(ws + 8 * MB);            // [8,24)  pq -> gemmQKV
  bf16* Tn    = (bf16*)(ws + 24 * MB);           // [24,40) ln -> mix
  bf16* ctxb  = (bf16*)(ws + 40 * MB);           // [40,56) mix -> gemmQKV
  bf16* Qa    = (bf16*)(ws + 56 * MB);           // [56,72) gemmQKV -> attn
  bf16* Ka    = (bf16*)(ws);                     // [0,16)  gemmQKV -> attn
  bf16* Vt    = (bf16*)(ws + 16 * MB);           // [16,32) gemmQKV -> attn
  bf16* oatt  = (bf16*)(ws + 32 * MB);           // [32,48) attn -> gemmO
  bf16* otmp  = (bf16*)(ws + 48 * MB);           // [48,64) gemmO -> orelay
  bf16* wib   = (bf16*)(ws + 72 * MB);
  bf16* wob   = (bf16*)(ws + 72 * MB + 1572864);

  k_wconv<<<1024, 256, 0, stream>>>(in_w, out_w, wib, wob);
  k_pq<<<dim3(64, 8), 256, 0, stream>>>(x, xp2t, qb);
  k_ln<<<dim3(256, 4), 512, 0, stream>>>(xp2t, ln_w, ln_b, Tn);
  k_mix<<<dim3(256, 2), 256, 0, stream>>>(Tn, mix_w, mix_b, ctxb);
  k_gemmQKV<<<dim3(128, 12), 256, 0, stream>>>(qb, ctxb, wib, in_b, Qa, Ka, Vt);
  k_attn<<<2048, 256, 0, stream>>>(Qa, Ka, Vt, oatt);
  k_gemmO<<<dim3(128, 4), 256, 0, stream>>>(oatt, wob, out_b, otmp);
  k_orelay<<<dim3(16, 8, 8), 256, 0, stream>>>(otmp, out);
}